// Round 3
// baseline (3318.816 us; speedup 1.0000x reference)
//
#include <hip/hip_runtime.h>

#define T_DIM 512
#define N_DIM 1024
#define K_DIM 2048
#define B_DIM 64

typedef _Float16 f16;
typedef _Float16 f16x8 __attribute__((ext_vector_type(8)));
typedef float f32x16 __attribute__((ext_vector_type(16)));

// 3-bit rotate permutation for 16B-slot swizzle: P(0..7) = {0,4,1,5,2,6,3,7}
#define PSWZ(r) ((((r) & 1) << 2) | (((r) >> 1) & 3))

// ---------------------------------------------------------------------------
// Kernel 1: z[b][t][n] = sum_i w[n][i]*x[b][i][t], f16x2 split on matrix cores.
// Block 128(n) x 256(t), 8 waves (2x4) of 64x64, BK=32, double-buffered LDS.
// Row layout (64 f16 = 128B): [c0 k0..31 | c1 k0..31], 8 slots of 16B,
// slot ^= PSWZ(row&7). All LDS writes are b128 (one slot) -> conflict-free.
// ---------------------------------------------------------------------------
__global__ __launch_bounds__(512, 2) void gemm_split(const float* __restrict__ x,
                                                     const float* __restrict__ w,
                                                     float* __restrict__ z) {
  const int bid = blockIdx.x;
  const int bn = bid & 7;
  const int tb = (bid >> 3) & 1;
  const int b  = bid >> 4;
  const int n0 = bn * 128, t0 = tb * 256;

  __shared__ f16 sA[2][128 * 64];  // 32 KB
  __shared__ f16 sB[2][256 * 64];  // 64 KB

  const int tid = threadIdx.x;
  const int lane = tid & 63;
  const int l31 = lane & 31;
  const int lhi = lane >> 5;
  const int wv = tid >> 6;   // 0..7
  const int wm = wv >> 2;    // 0..1  (n-dim)
  const int wt = wv & 3;     // 0..3  (t-dim)

  // A staging: row = tid>>2 (0..127), k-slot = tid&3 (8 k each)
  const int ar = tid >> 2;
  const int aks = tid & 3;
  const int Pa = PSWZ(ar & 7);
  const float* pA = w + (size_t)(n0 + ar) * K_DIM + aks * 8;
  // B staging: t-col = tid&255, k-half = tid>>8 (16 k each)
  const int btt = tid & 255;
  const int bkh = tid >> 8;
  const int Pb = PSWZ(btt & 7);
  const float* pB = x + (size_t)b * K_DIM * T_DIM + (size_t)(bkh * 16) * T_DIM + t0 + btt;

  // fragment read offsets
  const int Pl = PSWZ(l31 & 7);
  int sl[2][2];  // [comp][kc]
#pragma unroll
  for (int c = 0; c < 2; ++c)
#pragma unroll
    for (int kc = 0; kc < 2; ++kc)
      sl[c][kc] = ((((c << 2) | (kc << 1) | lhi) ^ Pl) << 3);
  const int rowA[2] = {(wm * 64 + l31) * 64, (wm * 64 + 32 + l31) * 64};
  const int rowB[2] = {(wt * 64 + l31) * 64, (wt * 64 + 32 + l31) * 64};

  f32x16 acc0[2][2], acc1[2][2];
#pragma unroll
  for (int i = 0; i < 2; ++i)
#pragma unroll
    for (int j = 0; j < 2; ++j)
#pragma unroll
      for (int r = 0; r < 16; ++r) {
        acc0[i][j][r] = 0.f;
        acc1[i][j][r] = 0.f;
      }

  float4 va0, va1;   // A staging regs (8 f32)
  float vb[16];      // B staging regs

#define LOAD_REGS(K0)                                                   \
  {                                                                     \
    va0 = *(const float4*)(pA + (K0));                                  \
    va1 = *(const float4*)(pA + (K0) + 4);                              \
    _Pragma("unroll")                                                   \
    for (int j = 0; j < 16; ++j) vb[j] = pB[(size_t)((K0) + j) * T_DIM];\
  }

#define STAGE_WRITE(AD, BD)                                             \
  {                                                                     \
    float av[8] = {va0.x, va0.y, va0.z, va0.w, va1.x, va1.y, va1.z, va1.w}; \
    f16x8 h0, h1;                                                       \
    _Pragma("unroll")                                                   \
    for (int q = 0; q < 8; ++q) {                                       \
      const float v = av[q] * 64.f;                                     \
      const f16 t_ = (f16)v;                                            \
      h0[q] = t_;                                                       \
      h1[q] = (f16)((v - (float)t_) * 4096.f);                          \
    }                                                                   \
    f16* rp = (AD) + ar * 64;                                           \
    *(f16x8*)&rp[(aks ^ Pa) << 3] = h0;                                 \
    *(f16x8*)&rp[((4 + aks) ^ Pa) << 3] = h1;                           \
    f16x8 g0a, g0b, g1a, g1b;                                           \
    _Pragma("unroll")                                                   \
    for (int q = 0; q < 8; ++q) {                                       \
      float v = vb[q];                                                  \
      f16 t_ = (f16)v;                                                  \
      g0a[q] = t_;                                                      \
      g1a[q] = (f16)((v - (float)t_) * 4096.f);                         \
      v = vb[8 + q];                                                    \
      t_ = (f16)v;                                                      \
      g0b[q] = t_;                                                      \
      g1b[q] = (f16)((v - (float)t_) * 4096.f);                         \
    }                                                                   \
    f16* rq = (BD) + btt * 64;                                          \
    *(f16x8*)&rq[((bkh * 2 + 0) ^ Pb) << 3] = g0a;                      \
    *(f16x8*)&rq[((bkh * 2 + 1) ^ Pb) << 3] = g0b;                      \
    *(f16x8*)&rq[((4 + bkh * 2 + 0) ^ Pb) << 3] = g1a;                  \
    *(f16x8*)&rq[((4 + bkh * 2 + 1) ^ Pb) << 3] = g1b;                  \
  }

#define MFMA_PHASE(AB, BB)                                              \
  {                                                                     \
    _Pragma("unroll")                                                   \
    for (int kc = 0; kc < 2; ++kc) {                                    \
      f16x8 A0[2], A1[2], B0[2], B1[2];                                 \
      _Pragma("unroll")                                                 \
      for (int f = 0; f < 2; ++f) {                                     \
        A0[f] = *(const f16x8*)&(AB)[rowA[f] + sl[0][kc]];              \
        A1[f] = *(const f16x8*)&(AB)[rowA[f] + sl[1][kc]];              \
        B0[f] = *(const f16x8*)&(BB)[rowB[f] + sl[0][kc]];              \
        B1[f] = *(const f16x8*)&(BB)[rowB[f] + sl[1][kc]];              \
      }                                                                 \
      _Pragma("unroll")                                                 \
      for (int f = 0; f < 2; ++f)                                       \
        _Pragma("unroll")                                               \
        for (int g = 0; g < 2; ++g) {                                   \
          acc0[f][g] = __builtin_amdgcn_mfma_f32_32x32x16_f16(A0[f], B0[g], acc0[f][g], 0, 0, 0); \
          acc1[f][g] = __builtin_amdgcn_mfma_f32_32x32x16_f16(A0[f], B1[g], acc1[f][g], 0, 0, 0); \
          acc1[f][g] = __builtin_amdgcn_mfma_f32_32x32x16_f16(A1[f], B0[g], acc1[f][g], 0, 0, 0); \
        }                                                               \
    }                                                                   \
  }

  // prologue
  LOAD_REGS(0);
  STAGE_WRITE(sA[0], sB[0]);
  LOAD_REGS(32);
  __syncthreads();

  int cur = 0;
  for (int it = 0; it < 64; ++it) {
    if (it < 63) STAGE_WRITE(sA[cur ^ 1], sB[cur ^ 1]);
    if (it < 62) LOAD_REGS((it + 2) * 32);
    if (cur == 0) {
      MFMA_PHASE(sA[0], sB[0]);
    } else {
      MFMA_PHASE(sA[1], sB[1]);
    }
    __syncthreads();
    cur ^= 1;
  }

#undef LOAD_REGS
#undef STAGE_WRITE
#undef MFMA_PHASE

  // epilogue: z = acc0/64 + acc1/(64*4096)
  float* zb = z + (size_t)b * T_DIM * N_DIM;
  const float C0 = 0.015625f;
  const float C1 = 3.814697265625e-06f;
#pragma unroll
  for (int f = 0; f < 2; ++f)
#pragma unroll
    for (int g = 0; g < 2; ++g) {
      const int tt = t0 + wt * 64 + g * 32 + l31;
      float* orow = zb + (size_t)tt * N_DIM + n0 + wm * 64 + f * 32 + lhi * 4;
#pragma unroll
      for (int q = 0; q < 4; ++q) {
        float4 o;
        o.x = acc0[f][g][4 * q + 0] * C0 + acc1[f][g][4 * q + 0] * C1;
        o.y = acc0[f][g][4 * q + 1] * C0 + acc1[f][g][4 * q + 1] * C1;
        o.z = acc0[f][g][4 * q + 2] * C0 + acc1[f][g][4 * q + 2] * C1;
        o.w = acc0[f][g][4 * q + 3] * C0 + acc1[f][g][4 * q + 3] * C1;
        *(float4*)(orow + q * 8) = o;
      }
    }
}

// ---------------------------------------------------------------------------
// Kernel 2: sequential CUBA-KWTA recurrence, ballot-based spike count.
// One block per batch, 256 threads, 4 neurons/thread, 8-deep prefetch ring.
// ---------------------------------------------------------------------------
__global__ __launch_bounds__(256) void kwta_scan(const float* __restrict__ z,
                                                 const float* __restrict__ se,
                                                 unsigned int* __restrict__ bits) {
  const int b = blockIdx.x;
  const int tid = threadIdx.x;
  const int lane = tid & 63;
  const int wid = tid >> 6;

  float a = se[0];
  a = fminf(fmaxf(a, 0.f), 1.f);
  const float ap1 = 1.f + a;
  const float RB = 0.8046875f;  // TH*(N-2K)/N/WS exact

  __shared__ float part[2][4];

  const float* zb = z + (size_t)b * T_DIM * N_DIM + tid * 4;
  unsigned int* gb = bits + (size_t)b * 16 * N_DIM + tid * 4;

  float4 r0 = *(const float4*)(zb);
  float4 r1 = *(const float4*)(zb + 1 * N_DIM);
  float4 r2 = *(const float4*)(zb + 2 * N_DIM);
  float4 r3 = *(const float4*)(zb + 3 * N_DIM);
  float4 r4 = *(const float4*)(zb + 4 * N_DIM);
  float4 r5 = *(const float4*)(zb + 5 * N_DIM);
  float4 r6 = *(const float4*)(zb + 6 * N_DIM);
  float4 r7 = *(const float4*)(zb + 7 * N_DIM);

  float u0 = 0.f, u1 = 0.f, u2 = 0.f, u3 = 0.f;
  float v0 = 0.f, v1 = 0.f, v2 = 0.f, v3 = 0.f;
  float s0 = 0.f, s1 = 0.f, s2 = 0.f, s3 = 0.f;
  float S = 0.f;
  unsigned int c0 = 0, c1 = 0, c2 = 0, c3 = 0;

#define NEU(U, V, SV, C, ZV)                            \
  {                                                     \
    const float fb  = fmaf(ap1, SV, -S) + RB;           \
    const float inp = ZV + fb;                          \
    U = fmaf(0.75f, U, inp);                            \
    V = fmaf(0.9f, V, U);                               \
    const bool sp = (V >= 1.0f);                        \
    SV = sp ? 1.0f : 0.0f;                              \
    V  = sp ? 0.0f : V;                                 \
    C |= ((unsigned int)sp) << (t & 31);                \
    msum += __popcll(__ballot(sp));                     \
  }

#define STEP(KK, RQ)                                                    \
  {                                                                     \
    const int t = tbase + KK;                                           \
    const float4 z4 = RQ;                                               \
    int tn = t + 8;                                                     \
    if (tn > 511) tn = 511;                                             \
    RQ = *(const float4*)(zb + (size_t)tn * N_DIM);                     \
    int msum = 0;                                                       \
    NEU(u0, v0, s0, c0, z4.x)                                           \
    NEU(u1, v1, s1, c1, z4.y)                                           \
    NEU(u2, v2, s2, c2, z4.z)                                           \
    NEU(u3, v3, s3, c3, z4.w)                                           \
    if (lane == 0) part[t & 1][wid] = (float)msum;                      \
    __syncthreads();                                                    \
    S = (part[t & 1][0] + part[t & 1][1]) +                             \
        (part[t & 1][2] + part[t & 1][3]);                              \
    if ((t & 31) == 31) {                                               \
      *(uint4*)(gb + (size_t)(t >> 5) * N_DIM) =                        \
          make_uint4(c0, c1, c2, c3);                                   \
      c0 = c1 = c2 = c3 = 0;                                            \
    }                                                                   \
  }

  for (int tbase = 0; tbase < T_DIM; tbase += 8) {
    STEP(0, r0)
    STEP(1, r1)
    STEP(2, r2)
    STEP(3, r3)
    STEP(4, r4)
    STEP(5, r5)
    STEP(6, r6)
    STEP(7, r7)
  }
#undef STEP
#undef NEU
}

// ---------------------------------------------------------------------------
// Kernel 3: expand bits -> out[b][n][t] fp32 with 1-step delay shift.
// ---------------------------------------------------------------------------
__global__ __launch_bounds__(256) void expand_out(const unsigned int* __restrict__ bits,
                                                  float* __restrict__ out) {
  const int gid = blockIdx.x * 256 + threadIdx.x;
  const int l = gid & 63;
  const int row = gid >> 6;
  const int b = row >> 10;
  const int n = row & 1023;
  const unsigned int* r = bits + (size_t)b * 16 * N_DIM + n;

  unsigned int byte;
  if (l == 0) {
    byte = (r[0] << 1) & 0xFFu;
  } else {
    const int src = 8 * l - 1;
    const int w0 = src >> 5;
    const unsigned int lo = r[(size_t)w0 * N_DIM];
    const unsigned int hi = (w0 < 15) ? r[(size_t)(w0 + 1) * N_DIM] : 0u;
    const unsigned long long comb = ((unsigned long long)hi << 32) | (unsigned long long)lo;
    byte = (unsigned int)(comb >> (src & 31)) & 0xFFu;
  }

  float f[8];
#pragma unroll
  for (int k = 0; k < 8; ++k) f[k] = (float)((byte >> k) & 1u);

  float* o = out + ((size_t)row << 9) + (l << 3);
  *reinterpret_cast<float4*>(o)     = make_float4(f[0], f[1], f[2], f[3]);
  *reinterpret_cast<float4*>(o + 4) = make_float4(f[4], f[5], f[6], f[7]);
}

// ---------------------------------------------------------------------------
extern "C" void kernel_launch(void* const* d_in, const int* in_sizes, int n_in,
                              void* d_out, int out_size, void* d_ws, size_t ws_size,
                              hipStream_t stream) {
  const float* x  = (const float*)d_in[0];   // [64][2048][512]
  const float* w  = (const float*)d_in[1];   // [1024][2048]
  const float* se = (const float*)d_in[2];   // [1]
  float* out = (float*)d_out;                // [64][1024][512] fp32
  unsigned int* bits = (unsigned int*)d_ws;  // [64][16][1024] u32 = 4 MB

  gemm_split<<<1024, 512, 0, stream>>>(x, w, out);
  kwta_scan<<<64, 256, 0, stream>>>(out, se, bits);
  expand_out<<<16384, 256, 0, stream>>>(bits, out);
}

// Round 4
// 3287.230 us; speedup vs baseline: 1.0096x; 1.0096x over previous
//
#include <hip/hip_runtime.h>

#define T_DIM 512
#define N_DIM 1024
#define K_DIM 2048

typedef _Float16 f16;
typedef _Float16 f16x4 __attribute__((ext_vector_type(4)));
typedef _Float16 f16x8 __attribute__((ext_vector_type(8)));
typedef float f32x16 __attribute__((ext_vector_type(16)));
typedef __attribute__((address_space(1))) const unsigned int GU32;
typedef __attribute__((address_space(3))) unsigned int LU32;

__device__ __forceinline__ void gload16(const void* g, void* l) {
  __builtin_amdgcn_global_load_lds((GU32*)g, (LU32*)l, 16, 0, 0);
}

// ---------------------------------------------------------------------------
// Kernel 0: pre-split w into f16 {w0, w1} laid out as the GEMM's A-LDS image:
// wimg[nt(4)][k16(128)][ (lhi*2+c)*256 + row ] * 8 f16   (16 KB per (nt,k16))
//   v = 64*w ; w0 = f16(v) ; w1 = f16((v - w0) * 4096)
// ---------------------------------------------------------------------------
__global__ __launch_bounds__(256) void presplit_w(const float* __restrict__ w,
                                                  f16* __restrict__ wimg) {
  const int gid = blockIdx.x * 256 + threadIdx.x;  // 262144
  const int ko = gid >> 10;   // k-octet 0..255
  const int n = gid & 1023;
  const float* src = w + (size_t)n * K_DIM + (ko << 3);
  const float4 v0 = *(const float4*)src;
  const float4 v1 = *(const float4*)(src + 4);
  const float vv[8] = {v0.x, v0.y, v0.z, v0.w, v1.x, v1.y, v1.z, v1.w};
  f16x8 h0, h1;
#pragma unroll
  for (int q = 0; q < 8; ++q) {
    const float v = vv[q] * 64.f;
    const f16 a = (f16)v;
    h0[q] = a;
    h1[q] = (f16)((v - (float)a) * 4096.f);
  }
  const int nt = n >> 8, row = n & 255;
  const int k16 = ko >> 1, lhi = ko & 1;
  f16* blk = wimg + (size_t)(nt * 128 + k16) * 8192;
  *(f16x8*)&blk[(((lhi << 1) | 0) * 256 + row) * 8] = h0;
  *(f16x8*)&blk[(((lhi << 1) | 1) * 256 + row) * 8] = h1;
}

// ---------------------------------------------------------------------------
// Kernel 1: z[b][t][n] = sum_i w[n][i]*x[b][i][t]  (z into d_out, [B][T][N])
// Block 256(n) x 128(t), 8 waves (4n x 2t) of 64x64, K-step 16, double-buffer.
// A staged via global_load_lds from pre-split wimg; x split in-register.
// acc0 += w0*x0 ; acc1 += w0*x1 + w1*x0 ; z = acc0/64 + acc1/(64*4096).
// ---------------------------------------------------------------------------
__global__ __launch_bounds__(512, 2) void gemm_split(const float* __restrict__ x,
                                                     const f16* __restrict__ wimg,
                                                     float* __restrict__ z) {
  const int p = blockIdx.x;
  const int lg = ((p & 7) << 7) | (p >> 3);  // bijective XCD swizzle (1024 % 8 == 0)
  const int nt = lg & 3;
  const int tt = (lg >> 2) & 3;
  const int b = lg >> 4;
  const int n0 = nt << 8, t0 = tt << 7;

  __shared__ f16 sA[2][8192];  // [buf][(lhi*2+c)*256 + row][8]  16 KB/buf
  __shared__ f16 sB[2][4096];  // [buf][(lhi*2+c)*128 + t][8]     8 KB/buf

  const int tid = threadIdx.x;
  const int lane = tid & 63;
  const int l31 = lane & 31, lhi = lane >> 5;
  const int wv = tid >> 6;   // 0..7
  const int wm = wv >> 1;    // 0..3 (n)
  const int wt = wv & 1;     // 0..1 (t)

  // x staging role: tcol 0..127, kq 0..3 (4 k-rows each)
  const int tcol = tid & 127, kq = tid >> 7;
  const float* pX = x + (size_t)b * (K_DIM * T_DIM) + (size_t)(kq << 2) * T_DIM + t0 + tcol;

  const f16* wbase = wimg + (size_t)nt * (128 * 8192);
  const int chunkelem = (wv * 2) * 512 + lane * 8;  // two 1KB chunks per wave

  // fragment read offsets (f16 elements)
  const int aoff0 = (((lhi << 1) | 0) * 256 + wm * 64 + l31) * 8;
  const int aoff1 = (((lhi << 1) | 1) * 256 + wm * 64 + l31) * 8;
  const int boff0 = (((lhi << 1) | 0) * 128 + wt * 64 + l31) * 8;
  const int boff1 = (((lhi << 1) | 1) * 128 + wt * 64 + l31) * 8;

  // x staging write offsets
  const int bwl = kq >> 1;
  const int bwq = (kq & 1) * 4;
  const int bso0 = (((bwl << 1) | 0) * 128 + tcol) * 8 + bwq;
  const int bso1 = (((bwl << 1) | 1) * 128 + tcol) * 8 + bwq;

  f32x16 acc0[2][2], acc1[2][2];
#pragma unroll
  for (int i = 0; i < 2; ++i)
#pragma unroll
    for (int j = 0; j < 2; ++j)
#pragma unroll
      for (int r = 0; r < 16; ++r) {
        acc0[i][j][r] = 0.f;
        acc1[i][j][r] = 0.f;
      }

  float xv0, xv1, xv2, xv3;

#define LOADX(IT)                                                       \
  {                                                                     \
    const size_t ro = (size_t)((IT) * 16) * T_DIM;                      \
    xv0 = pX[ro];                                                       \
    xv1 = pX[ro + T_DIM];                                               \
    xv2 = pX[ro + 2 * T_DIM];                                           \
    xv3 = pX[ro + 3 * T_DIM];                                           \
  }

#define STAGE(BUF, IT)                                                  \
  {                                                                     \
    const f16* ws = wbase + (size_t)(IT) * 8192 + chunkelem;            \
    gload16(ws, &sA[BUF][chunkelem]);                                   \
    gload16(ws + 512, &sA[BUF][chunkelem + 512]);                       \
    f16x4 g0, g1;                                                       \
    { const float v = xv0; const f16 a = (f16)v; g0[0] = a; g1[0] = (f16)((v - (float)a) * 4096.f); } \
    { const float v = xv1; const f16 a = (f16)v; g0[1] = a; g1[1] = (f16)((v - (float)a) * 4096.f); } \
    { const float v = xv2; const f16 a = (f16)v; g0[2] = a; g1[2] = (f16)((v - (float)a) * 4096.f); } \
    { const float v = xv3; const f16 a = (f16)v; g0[3] = a; g1[3] = (f16)((v - (float)a) * 4096.f); } \
    *(f16x4*)&sB[BUF][bso0] = g0;                                       \
    *(f16x4*)&sB[BUF][bso1] = g1;                                       \
  }

#define COMPUTE(BUF)                                                    \
  {                                                                     \
    f16x8 a0[2], a1[2], b0[2], b1[2];                                   \
    a0[0] = *(const f16x8*)&sA[BUF][aoff0];                             \
    a0[1] = *(const f16x8*)&sA[BUF][aoff0 + 32 * 8];                    \
    a1[0] = *(const f16x8*)&sA[BUF][aoff1];                             \
    a1[1] = *(const f16x8*)&sA[BUF][aoff1 + 32 * 8];                    \
    b0[0] = *(const f16x8*)&sB[BUF][boff0];                             \
    b0[1] = *(const f16x8*)&sB[BUF][boff0 + 32 * 8];                    \
    b1[0] = *(const f16x8*)&sB[BUF][boff1];                             \
    b1[1] = *(const f16x8*)&sB[BUF][boff1 + 32 * 8];                    \
    _Pragma("unroll")                                                   \
    for (int f = 0; f < 2; ++f)                                         \
      _Pragma("unroll")                                                 \
      for (int g = 0; g < 2; ++g) {                                     \
        acc0[f][g] = __builtin_amdgcn_mfma_f32_32x32x16_f16(a0[f], b0[g], acc0[f][g], 0, 0, 0); \
        acc1[f][g] = __builtin_amdgcn_mfma_f32_32x32x16_f16(a0[f], b1[g], acc1[f][g], 0, 0, 0); \
        acc1[f][g] = __builtin_amdgcn_mfma_f32_32x32x16_f16(a1[f], b0[g], acc1[f][g], 0, 0, 0); \
      }                                                                 \
  }

  // prologue
  LOADX(0);
  STAGE(0, 0);
  LOADX(1);
  __syncthreads();

  int cur = 0;
  for (int it = 0; it < 128; ++it) {
    if (it < 127) STAGE(cur ^ 1, it + 1);
    if (it < 126) LOADX(it + 2);
    if (cur == 0) {
      COMPUTE(0);
    } else {
      COMPUTE(1);
    }
    __syncthreads();
    cur ^= 1;
  }

#undef LOADX
#undef STAGE
#undef COMPUTE

  // epilogue: z = acc0/64 + acc1/(64*4096), stored z[t][n]
  float* zb = z + (size_t)b * T_DIM * N_DIM;
  const float C0 = 0.015625f;
  const float C1 = 3.814697265625e-06f;
#pragma unroll
  for (int f = 0; f < 2; ++f)
#pragma unroll
    for (int g = 0; g < 2; ++g) {
      const int t = t0 + wt * 64 + g * 32 + l31;
      float* orow = zb + (size_t)t * N_DIM + n0 + wm * 64 + f * 32 + lhi * 4;
#pragma unroll
      for (int q = 0; q < 4; ++q) {
        float4 o;
        o.x = acc0[f][g][4 * q + 0] * C0 + acc1[f][g][4 * q + 0] * C1;
        o.y = acc0[f][g][4 * q + 1] * C0 + acc1[f][g][4 * q + 1] * C1;
        o.z = acc0[f][g][4 * q + 2] * C0 + acc1[f][g][4 * q + 2] * C1;
        o.w = acc0[f][g][4 * q + 3] * C0 + acc1[f][g][4 * q + 3] * C1;
        *(float4*)(orow + q * 8) = o;
      }
    }
}

// ---------------------------------------------------------------------------
// Kernel 2: sequential CUBA-KWTA recurrence, ballot-based spike count.
// ---------------------------------------------------------------------------
__global__ __launch_bounds__(256) void kwta_scan(const float* __restrict__ z,
                                                 const float* __restrict__ se,
                                                 unsigned int* __restrict__ bits) {
  const int b = blockIdx.x;
  const int tid = threadIdx.x;
  const int lane = tid & 63;
  const int wid = tid >> 6;

  float a = se[0];
  a = fminf(fmaxf(a, 0.f), 1.f);
  const float ap1 = 1.f + a;
  const float RB = 0.8046875f;  // TH*(N-2K)/N/WS exact

  __shared__ float part[2][4];

  const float* zb = z + (size_t)b * T_DIM * N_DIM + tid * 4;
  unsigned int* gb = bits + (size_t)b * 16 * N_DIM + tid * 4;

  float4 r0 = *(const float4*)(zb);
  float4 r1 = *(const float4*)(zb + 1 * N_DIM);
  float4 r2 = *(const float4*)(zb + 2 * N_DIM);
  float4 r3 = *(const float4*)(zb + 3 * N_DIM);
  float4 r4 = *(const float4*)(zb + 4 * N_DIM);
  float4 r5 = *(const float4*)(zb + 5 * N_DIM);
  float4 r6 = *(const float4*)(zb + 6 * N_DIM);
  float4 r7 = *(const float4*)(zb + 7 * N_DIM);

  float u0 = 0.f, u1 = 0.f, u2 = 0.f, u3 = 0.f;
  float v0 = 0.f, v1 = 0.f, v2 = 0.f, v3 = 0.f;
  float s0 = 0.f, s1 = 0.f, s2 = 0.f, s3 = 0.f;
  float S = 0.f;
  unsigned int c0 = 0, c1 = 0, c2 = 0, c3 = 0;

#define NEU(U, V, SV, C, ZV)                            \
  {                                                     \
    const float fb  = fmaf(ap1, SV, -S) + RB;           \
    const float inp = ZV + fb;                          \
    U = fmaf(0.75f, U, inp);                            \
    V = fmaf(0.9f, V, U);                               \
    const bool sp = (V >= 1.0f);                        \
    SV = sp ? 1.0f : 0.0f;                              \
    V  = sp ? 0.0f : V;                                 \
    C |= ((unsigned int)sp) << (t & 31);                \
    msum += __popcll(__ballot(sp));                     \
  }

#define STEP(KK, RQ)                                                    \
  {                                                                     \
    const int t = tbase + KK;                                           \
    const float4 z4 = RQ;                                               \
    int tn = t + 8;                                                     \
    if (tn > 511) tn = 511;                                             \
    RQ = *(const float4*)(zb + (size_t)tn * N_DIM);                     \
    int msum = 0;                                                       \
    NEU(u0, v0, s0, c0, z4.x)                                           \
    NEU(u1, v1, s1, c1, z4.y)                                           \
    NEU(u2, v2, s2, c2, z4.z)                                           \
    NEU(u3, v3, s3, c3, z4.w)                                           \
    if (lane == 0) part[t & 1][wid] = (float)msum;                      \
    __syncthreads();                                                    \
    S = (part[t & 1][0] + part[t & 1][1]) +                             \
        (part[t & 1][2] + part[t & 1][3]);                              \
    if ((t & 31) == 31) {                                               \
      *(uint4*)(gb + (size_t)(t >> 5) * N_DIM) =                        \
          make_uint4(c0, c1, c2, c3);                                   \
      c0 = c1 = c2 = c3 = 0;                                            \
    }                                                                   \
  }

  for (int tbase = 0; tbase < T_DIM; tbase += 8) {
    STEP(0, r0)
    STEP(1, r1)
    STEP(2, r2)
    STEP(3, r3)
    STEP(4, r4)
    STEP(5, r5)
    STEP(6, r6)
    STEP(7, r7)
  }
#undef STEP
#undef NEU
}

// ---------------------------------------------------------------------------
// Kernel 3: expand bits -> out[b][n][t] fp32 with 1-step delay shift.
// ---------------------------------------------------------------------------
__global__ __launch_bounds__(256) void expand_out(const unsigned int* __restrict__ bits,
                                                  float* __restrict__ out) {
  const int gid = blockIdx.x * 256 + threadIdx.x;
  const int l = gid & 63;
  const int row = gid >> 6;
  const int b = row >> 10;
  const int n = row & 1023;
  const unsigned int* r = bits + (size_t)b * 16 * N_DIM + n;

  unsigned int byte;
  if (l == 0) {
    byte = (r[0] << 1) & 0xFFu;
  } else {
    const int src = 8 * l - 1;
    const int w0 = src >> 5;
    const unsigned int lo = r[(size_t)w0 * N_DIM];
    const unsigned int hi = (w0 < 15) ? r[(size_t)(w0 + 1) * N_DIM] : 0u;
    const unsigned long long comb = ((unsigned long long)hi << 32) | (unsigned long long)lo;
    byte = (unsigned int)(comb >> (src & 31)) & 0xFFu;
  }

  float f[8];
#pragma unroll
  for (int k = 0; k < 8; ++k) f[k] = (float)((byte >> k) & 1u);

  float* o = out + ((size_t)row << 9) + (l << 3);
  *reinterpret_cast<float4*>(o)     = make_float4(f[0], f[1], f[2], f[3]);
  *reinterpret_cast<float4*>(o + 4) = make_float4(f[4], f[5], f[6], f[7]);
}

// ---------------------------------------------------------------------------
extern "C" void kernel_launch(void* const* d_in, const int* in_sizes, int n_in,
                              void* d_out, int out_size, void* d_ws, size_t ws_size,
                              hipStream_t stream) {
  const float* x  = (const float*)d_in[0];   // [64][2048][512]
  const float* w  = (const float*)d_in[1];   // [1024][2048]
  const float* se = (const float*)d_in[2];   // [1]
  float* out = (float*)d_out;                // [64][1024][512] fp32

  // wimg occupies d_ws[0, 8MB); bits reuses d_ws[0, 4MB) AFTER gemm (wimg dead)
  f16* wimg = (f16*)d_ws;
  unsigned int* bits = (unsigned int*)d_ws;

  presplit_w<<<1024, 256, 0, stream>>>(w, wimg);
  gemm_split<<<1024, 512, 0, stream>>>(x, wimg, out);
  kwta_scan<<<64, 256, 0, stream>>>(out, se, bits);
  expand_out<<<16384, 256, 0, stream>>>(bits, out);
}